// Round 2
// 131.039 us; speedup vs baseline: 1.0420x; 1.0420x over previous
//
#include <hip/hip_runtime.h>
#include <hip/hip_bf16.h>
#include <stdint.h>

// Problem: B=4, C=256, O=256, H=W=64, K=3, K2=9, KK=2304
// ws: xT bf16 NHWC @0 (8388608) | yT @8388608 (8388608) | Wp2 @16777216
//     (1179648) | Bo (+147456)

typedef __bf16 bf16x8 __attribute__((ext_vector_type(8)));
typedef float  f32x4  __attribute__((ext_vector_type(4)));

__device__ __forceinline__ unsigned short f2bfu(float f) {
    union { float f; unsigned u; } v; v.f = f;
    return (unsigned short)((v.u + 0x8000u) >> 16);
}
__device__ __forceinline__ float lo16(unsigned u) {
    union { unsigned u; float f; } v; v.u = u << 16; return v.f;
}
__device__ __forceinline__ float hi16(unsigned u) {
    union { unsigned u; float f; } v; v.u = u & 0xFFFF0000u; return v.f;
}
__device__ __forceinline__ unsigned fbits(float f) {
    union { float f; unsigned u; } v; v.f = f; return v.u;
}
__device__ __forceinline__ unsigned blend2(unsigned u0, unsigned u1, unsigned u2, unsigned u3,
                                           float4 w) {
    float lo = w.x * lo16(u0) + w.y * lo16(u1) + w.z * lo16(u2) + w.w * lo16(u3);
    float hi = w.x * hi16(u0) + w.y * hi16(u1) + w.z * hi16(u2) + w.w * hi16(u3);
    unsigned rl = fbits(lo) + 0x8000u;
    unsigned rh = fbits(hi) + 0x8000u;
    return __builtin_amdgcn_perm(rh, rl, 0x07060302);
}

// ---------------------------------------------------------------------------
// prep: fused {x,y transpose to NHWC bf16} + {packw} + {packow}.
// ---------------------------------------------------------------------------
__global__ __launch_bounds__(256) void prep_kernel(
    const float* __restrict__ x, const float* __restrict__ y,
    const float* __restrict__ ow, const float* __restrict__ dw,
    unsigned short* __restrict__ xT, unsigned short* __restrict__ yT,
    unsigned short* __restrict__ Wp2, unsigned short* __restrict__ Bo)
{
    __shared__ float tile[64 * 69];
    int blk = blockIdx.x;
    int t = threadIdx.x;
    if (blk < 2048) {
        const float* src = x; unsigned short* dst = xT;
        if (blk >= 1024) { src = y; dst = yT; blk -= 1024; }
        int cq = blk & 3;
        int bh = blk >> 2;
        int w4 = t & 15, cl0 = t >> 4;
        const float* s = src + ((size_t)(bh >> 6) * 256 + cq * 64) * 4096 + (size_t)(bh & 63) * 64;
#pragma unroll
        for (int p = 0; p < 4; ++p) {
            int cl = p * 16 + cl0;
            float4 v = *(const float4*)&s[(size_t)cl * 4096 + w4 * 4];
            tile[(w4 * 4 + 0) * 69 + cl] = v.x;
            tile[(w4 * 4 + 1) * 69 + cl] = v.y;
            tile[(w4 * 4 + 2) * 69 + cl] = v.z;
            tile[(w4 * 4 + 3) * 69 + cl] = v.w;
        }
        __syncthreads();
        unsigned short* d = dst + (size_t)bh * 16384 + cq * 64;
#pragma unroll
        for (int p = 0; p < 4; ++p) {
            int w = p * 16 + cl0;
            float4 v = *(const float4*)&tile[w * 69 + w4 * 4];
            ushort4 r = make_ushort4(f2bfu(v.x), f2bfu(v.y), f2bfu(v.z), f2bfu(v.w));
            *(ushort4*)&d[w * 256 + w4 * 4] = r;
        }
    } else if (blk < 2336) {
        int tid = (blk - 2048) * 256 + t;
        int q8 = tid >> 8;
        int o  = tid & 255;
        int k0 = q8 * 8;
        int tap = k0 >> 8, c0 = k0 & 255;
        const float* s = dw + o * 2304 + c0 * 9 + tap;
        ushort4 r0 = make_ushort4(f2bfu(s[0]), f2bfu(s[9]), f2bfu(s[18]), f2bfu(s[27]));
        ushort4 r1 = make_ushort4(f2bfu(s[36]), f2bfu(s[45]), f2bfu(s[54]), f2bfu(s[63]));
        *(ushort4*)&Wp2[tid * 8 + 0] = r0;
        *(ushort4*)&Wp2[tid * 8 + 4] = r1;
    } else {
        int idx = (blk - 2336) * 256 + t;
        int j = idx & 7;
        int n = (idx >> 3) & 31;
        int lq = (idx >> 8) & 3;
        int kg = idx >> 10;
        int k = kg * 32 + lq * 8 + j;
        int tap = k >> 8, c = k & 255;
        float v = (n < 18) ? ow[n * 2304 + c * 9 + tap] : 0.f;
        Bo[idx] = f2bfu(v);
    }
}

// ---------------------------------------------------------------------------
// Fused deform: grid 256 = (b,h), 1024 threads = 16 waves.
// Main loop restructure vs round-0 version:
//   - 4 LDS A-buffers (tap&3), ONE barrier per 2 taps (was 1/tap): waves may
//     drift a full 2-tap window so gather/blend VALU, LDS, L2 and MFMA pipes
//     overlap across waves instead of phase-locking.
//   - sched_barrier(0) right after gather-issue pins the 8 global loads
//     BEFORE the MFMA phase (round-0 build: VGPR_Count=64 proves the
//     allocator sank them to just before the blend, exposing L2 latency
//     every tap).
//   - s_setprio(1/0) around each tap's MFMA cluster (T5).
// ---------------------------------------------------------------------------

struct GatherRegs { uint4 ga[2][4]; float4 gw[2]; };

__device__ __forceinline__ void issue_tap(GatherRegs& G, int tap, int t,
                                          const unsigned short* __restrict__ xtb, int c0,
                                          const float4* __restrict__ pw_lds,
                                          const int4* __restrict__ pi_lds)
{
#pragma unroll
    for (int it = 0; it < 2; ++it) {
        int pos = (t >> 5) + it * 32;
        G.gw[it] = pw_lds[tap * 64 + pos];
        int4 p = pi_lds[tap * 64 + pos];
        G.ga[it][0] = *(const uint4*)&xtb[p.x + c0];
        G.ga[it][1] = *(const uint4*)&xtb[p.y + c0];
        G.ga[it][2] = *(const uint4*)&xtb[p.z + c0];
        G.ga[it][3] = *(const uint4*)&xtb[p.w + c0];
    }
}

__device__ __forceinline__ void commit_tap(const GatherRegs& G, unsigned short* buf,
                                           int t, int gr)
{
#pragma unroll
    for (int it = 0; it < 2; ++it) {
        int pos = (t >> 5) + it * 32;
        uint4 res;
        res.x = blend2(G.ga[it][0].x, G.ga[it][1].x, G.ga[it][2].x, G.ga[it][3].x, G.gw[it]);
        res.y = blend2(G.ga[it][0].y, G.ga[it][1].y, G.ga[it][2].y, G.ga[it][3].y, G.gw[it]);
        res.z = blend2(G.ga[it][0].z, G.ga[it][1].z, G.ga[it][2].z, G.ga[it][3].z, G.gw[it]);
        res.w = blend2(G.ga[it][0].w, G.ga[it][1].w, G.ga[it][2].w, G.ga[it][3].w, G.gw[it]);
        *(uint4*)&buf[pos * 256 + (gr ^ (pos & 7)) * 8] = res;
    }
}

__device__ __forceinline__ void mfma_tap(f32x4 (&acc)[4][2],
                                         const unsigned short* __restrict__ Ab,
                                         const unsigned short* __restrict__ Wp2,
                                         int tap, int kh, int lq, int ln, int ns)
{
    __builtin_amdgcn_s_setprio(1);
#pragma unroll
    for (int kc = 0; kc < 4; ++kc) {
        int gbase = kh * 16 + kc * 4 + lq;
        bf16x8 af[4];
#pragma unroll
        for (int ms = 0; ms < 4; ++ms) {
            int row = ms * 16 + ln;
            af[ms] = *(const bf16x8*)&Ab[row * 256 + (gbase ^ (row & 7)) * 8];
        }
        int kg = tap * 8 + kh * 4 + kc;
        bf16x8 bfr[2];
#pragma unroll
        for (int nt = 0; nt < 2; ++nt)
            bfr[nt] = *(const bf16x8*)&Wp2[((kg * 4 + lq) * 256 + ns * 32 + nt * 16 + ln) * 8];
#pragma unroll
        for (int ms = 0; ms < 4; ++ms)
#pragma unroll
            for (int nt = 0; nt < 2; ++nt)
                acc[ms][nt] = __builtin_amdgcn_mfma_f32_16x16x32_bf16(af[ms], bfr[nt], acc[ms][nt], 0, 0, 0);
    }
    __builtin_amdgcn_s_setprio(0);
}

__global__ __launch_bounds__(1024) void deform_kernel(
    const unsigned short* __restrict__ xT,
    const unsigned short* __restrict__ yT,
    const unsigned short* __restrict__ Wp2,
    const unsigned short* __restrict__ Bo,
    const float* __restrict__ ob,
    const float* __restrict__ db,
    float* __restrict__ out)
{
    __shared__ __align__(16) unsigned char smem[149504];
    unsigned short* Abase = (unsigned short*)smem;             // 4 x 32768 B
    float*  red = (float*)smem;                                // 16*1056*4 = 67584 B
    float*  epi = (float*)smem;                                // 8*2176*4 = 69632 B
    float4* pw_lds = (float4*)(smem + 131072);                 // 9216 B
    int4*   pi_lds = (int4*)(smem + 131072 + 9216);            // 9216 B

    int blk = blockIdx.x;
    int lb = (blk & 7) * 32 + (blk >> 3);        // XCD-slab swizzle
    int b = lb >> 6, h = lb & 63;
    int t = threadIdx.x;
    int wv = t >> 6, lane = t & 63;
    int ln = lane & 15, lq = lane >> 4;

    const unsigned short* xtb = xT + (size_t)b * (64 * 64 * 256);

    // ================= offsets prologue =================
    {
        int kq = wv >> 1, mh = wv & 1;
        f32x4 oacc[2][2];
#pragma unroll
        for (int m16 = 0; m16 < 2; ++m16)
#pragma unroll
            for (int nt = 0; nt < 2; ++nt)
                oacc[m16][nt] = (f32x4){0.f, 0.f, 0.f, 0.f};
        for (int u = kq * 9; u < kq * 9 + 9; ++u) {
            int tap = u >> 3, kc = u & 7;
            int ki = tap / 3, kj = tap - ki * 3;
            int hr = h + ki - 1;
            bf16x8 b0 = *(const bf16x8*)&Bo[(tap * 8 + kc) * 1024 + lq * 256 + ln * 8];
            bf16x8 b1 = *(const bf16x8*)&Bo[(tap * 8 + kc) * 1024 + lq * 256 + (16 + ln) * 8];
#pragma unroll
            for (int m16 = 0; m16 < 2; ++m16) {
                int wr = mh * 32 + m16 * 16 + ln + kj - 1;
                bf16x8 af = (bf16x8)(__bf16)0.0f;
                if (hr >= 0 && hr < 64 && wr >= 0 && wr < 64)
                    af = *(const bf16x8*)&yT[((size_t)(b * 64 + hr) * 64 + wr) * 256 + kc * 32 + lq * 8];
                oacc[m16][0] = __builtin_amdgcn_mfma_f32_16x16x32_bf16(af, b0, oacc[m16][0], 0, 0, 0);
                oacc[m16][1] = __builtin_amdgcn_mfma_f32_16x16x32_bf16(af, b1, oacc[m16][1], 0, 0, 0);
            }
        }
        float* rz = red + (size_t)(kq * 2 + mh) * 1056;
#pragma unroll
        for (int m16 = 0; m16 < 2; ++m16)
#pragma unroll
            for (int nt = 0; nt < 2; ++nt) {
                int o_l = nt * 16 + ln;
#pragma unroll
                for (int r = 0; r < 4; ++r)
                    rz[o_l * 33 + m16 * 16 + lq * 4 + r] = oacc[m16][nt][r];
            }
    }
    __syncthreads();
    // params: 576 jobs = (tap, pos)
    if (t < 576) {
        int tap = t >> 6, pos = t & 63;
        int mh_p = pos >> 5, pl = pos & 31;
        float dy = ob[2 * tap], dx = ob[2 * tap + 1];
#pragma unroll
        for (int kq = 0; kq < 8; ++kq) {
            const float* rz = red + (size_t)(kq * 2 + mh_p) * 1056;
            dy += rz[(2 * tap) * 33 + pl];
            dx += rz[(2 * tap + 1) * 33 + pl];
        }
        int ki = tap / 3, kj = tap - ki * 3;
        float py = (float)(h - 1 + ki) + dy;
        float px = (float)(pos - 1 + kj) + dx;
        float y0 = floorf(py), x0 = floorf(px);
        float wy1 = py - y0, wx1 = px - x0;
        float wy0 = 1.f - wy1, wx0 = 1.f - wx1;
        float y1 = y0 + 1.f, x1 = x0 + 1.f;
        float vy0 = (y0 >= 0.f && y0 <= 63.f) ? 1.f : 0.f;
        float vy1 = (y1 >= 0.f && y1 <= 63.f) ? 1.f : 0.f;
        float vx0 = (x0 >= 0.f && x0 <= 63.f) ? 1.f : 0.f;
        float vx1 = (x1 >= 0.f && x1 <= 63.f) ? 1.f : 0.f;
        int iy0 = (int)fminf(fmaxf(y0, 0.f), 63.f);
        int iy1 = (int)fminf(fmaxf(y1, 0.f), 63.f);
        int ix0 = (int)fminf(fmaxf(x0, 0.f), 63.f);
        int ix1 = (int)fminf(fmaxf(x1, 0.f), 63.f);
        pw_lds[t] = make_float4(wy0 * wx0 * vy0 * vx0, wy0 * wx1 * vy0 * vx1,
                                wy1 * wx0 * vy1 * vx0, wy1 * wx1 * vy1 * vx1);
        pi_lds[t] = make_int4((iy0 * 64 + ix0) * 256, (iy0 * 64 + ix1) * 256,
                              (iy1 * 64 + ix0) * 256, (iy1 * 64 + ix1) * 256);
    }
    __syncthreads();

    // ================= main implicit GEMM =================
    int ns = wv & 7, kh = wv >> 3;

    f32x4 acc[4][2];
#pragma unroll
    for (int ms = 0; ms < 4; ++ms)
#pragma unroll
        for (int nt = 0; nt < 2; ++nt)
            acc[ms][nt] = (f32x4){0.f, 0.f, 0.f, 0.f};

    int gr = t & 31, c0 = gr * 8;
    GatherRegs G;

    // stage taps 0 and 1
    issue_tap(G, 0, t, xtb, c0, pw_lds, pi_lds);
    commit_tap(G, Abase + 0 * 16384, t, gr);
    issue_tap(G, 1, t, xtb, c0, pw_lds, pi_lds);
    commit_tap(G, Abase + 1 * 16384, t, gr);
    __syncthreads();

    for (int i = 0; i < 4; ++i) {
        int tp0 = 2 * i, tp1 = 2 * i + 1;
        int s0 = tp0 + 2, s1 = tp1 + 2;
        // prefetch tap s0 -- pinned before the MFMA phase
        issue_tap(G, s0, t, xtb, c0, pw_lds, pi_lds);
        __builtin_amdgcn_sched_barrier(0);
        mfma_tap(acc, Abase + (tp0 & 3) * 16384, Wp2, tp0, kh, lq, ln, ns);
        commit_tap(G, Abase + (s0 & 3) * 16384, t, gr);
        if (s1 < 9) {
            issue_tap(G, s1, t, xtb, c0, pw_lds, pi_lds);
            __builtin_amdgcn_sched_barrier(0);
        }
        mfma_tap(acc, Abase + (tp1 & 3) * 16384, Wp2, tp1, kh, lq, ln, ns);
        if (s1 < 9)
            commit_tap(G, Abase + (s1 & 3) * 16384, t, gr);
        __syncthreads();
    }
    mfma_tap(acc, Abase + 0 * 16384, Wp2, 8, kh, lq, ln, ns);
    __syncthreads();

    // ================= epilogue =================
    if (kh == 1) {
        float* e = epi + (size_t)ns * 2176;
#pragma unroll
        for (int ms = 0; ms < 4; ++ms)
#pragma unroll
            for (int nt = 0; nt < 2; ++nt) {
                int o_l = nt * 16 + ln;
                f32x4 a = acc[ms][nt];
                *(float4*)&e[o_l * 68 + ms * 16 + lq * 4] = make_float4(a[0], a[1], a[2], a[3]);
            }
    }
    __syncthreads();
    if (kh == 0) {
        const float* e = epi + (size_t)ns * 2176;
#pragma unroll
        for (int ms = 0; ms < 4; ++ms)
#pragma unroll
            for (int nt = 0; nt < 2; ++nt) {
                int o_l = nt * 16 + ln;
                int o = ns * 32 + o_l;
                float bias = db[o];
                float4 p = *(const float4*)&e[o_l * 68 + ms * 16 + lq * 4];
                f32x4 a = acc[ms][nt];
                float4 st = make_float4(a[0] + p.x + bias, a[1] + p.y + bias,
                                        a[2] + p.z + bias, a[3] + p.w + bias);
                *(float4*)&out[((size_t)(b * 256 + o)) * 4096 + h * 64 + ms * 16 + lq * 4] = st;
            }
    }
}

extern "C" void kernel_launch(void* const* d_in, const int* in_sizes, int n_in,
                              void* d_out, int out_size, void* d_ws, size_t ws_size,
                              hipStream_t stream) {
    const float* x  = (const float*)d_in[0];
    const float* y  = (const float*)d_in[1];
    const float* ow = (const float*)d_in[2];
    const float* ob = (const float*)d_in[3];
    const float* dw = (const float*)d_in[4];
    const float* db = (const float*)d_in[5];
    float* out = (float*)d_out;

    char* ws = (char*)d_ws;
    unsigned short* xT  = (unsigned short*)(ws);
    unsigned short* yT  = (unsigned short*)(ws + 8388608);
    unsigned short* Wp2 = (unsigned short*)(ws + 16777216);
    unsigned short* Bo  = (unsigned short*)(ws + 16777216 + 1179648);

    hipLaunchKernelGGL(prep_kernel, dim3(2624), dim3(256), 0, stream,
                       x, y, ow, dw, xT, yT, Wp2, Bo);
    hipLaunchKernelGGL(deform_kernel, dim3(256), dim3(1024), 0, stream,
                       xT, yT, Wp2, Bo, ob, db, out);
}